// Round 3
// baseline (307.594 us; speedup 1.0000x reference)
//
#include <hip/hip_runtime.h>

#define DIM 64
#define ICH 32
#define OCH 64
#define SPA (DIM*DIM*DIM)   // 262144

typedef short  s16x8  __attribute__((ext_vector_type(8)));
typedef float  f32x16 __attribute__((ext_vector_type(16)));

__device__ __forceinline__ short f2bf(float f) {   // fp32 -> bf16 bits, RNE
    unsigned u = __float_as_uint(f);
    return (short)((u + 0x7fffu + ((u >> 16) & 1u)) >> 16);
}
__device__ __forceinline__ unsigned pk2bf(float lo, float hi) {
    return (unsigned)(unsigned short)f2bf(lo) | ((unsigned)(unsigned short)f2bf(hi) << 16);
}
// LDS XOR swizzle (involution, applied to byte addresses on write AND read)
__device__ __forceinline__ int swz(int a) { return a ^ (((a >> 7) & 7) << 4); }

// =================================================================
// FAST PATH
// =================================================================

// ---- Prepass: x (fp32, [b][c][d][h][w]) -> xT (bf16, [b][d][h][w][c32]),
// ---- with fused GAP partial sums: partial[(b*32+c)*1024 + d*16+hq].
// grid 2048 = b(2) * d(64) * hq(16); 4 h-rows per block; 256 threads.
__global__ __launch_bounds__(256) void prepass_kernel(const float* __restrict__ x,
                                                      short* __restrict__ xT,
                                                      float* __restrict__ partial) {
    __shared__ unsigned lds32[64 * 17];   // [w][cpair] padded +1 dword
    __shared__ float pacc[32];

    int bid = blockIdx.x;
    int hq = bid & 15, d = (bid >> 4) & 63, b = bid >> 10;
    int t = threadIdx.x;
    int cp = t >> 4;            // 0..15 -> channels 2cp, 2cp+1
    int wg = t & 15;            // 0..15 -> w = wg*4 .. +3

    float acc0 = 0.f, acc1 = 0.f;

    for (int r = 0; r < 4; ++r) {
        int h = hq * 4 + r;
        const float* s0 = x + (size_t)(b * ICH + 2 * cp) * SPA + (d * 4096 + h * 64 + wg * 4);
        float4 a = *(const float4*)s0;
        float4 c = *(const float4*)(s0 + SPA);
        acc0 += (a.x + a.y) + (a.z + a.w);
        acc1 += (c.x + c.y) + (c.z + c.w);
        __syncthreads();
        lds32[(wg * 4 + 0) * 17 + cp] = pk2bf(a.x, c.x);
        lds32[(wg * 4 + 1) * 17 + cp] = pk2bf(a.y, c.y);
        lds32[(wg * 4 + 2) * 17 + cp] = pk2bf(a.z, c.z);
        lds32[(wg * 4 + 3) * 17 + cp] = pk2bf(a.w, c.w);
        __syncthreads();
        // read back [w][c0..c0+7] and store 16B to xT
        int w = t >> 2, q = t & 3;
        uint4 v;
        v.x = lds32[w * 17 + q * 4 + 0];
        v.y = lds32[w * 17 + q * 4 + 1];
        v.z = lds32[w * 17 + q * 4 + 2];
        v.w = lds32[w * 17 + q * 4 + 3];
        *(uint4*)(xT + ((size_t)((b * 64 + d) * 64 + h) * 64 + w) * 32 + q * 8) = v;
    }
    // pool reduce: within wave, sum over wg (16 lanes, stride 1 inside cp group)
#pragma unroll
    for (int off = 1; off < 16; off <<= 1) {
        acc0 += __shfl_down(acc0, off, 64);
        acc1 += __shfl_down(acc1, off, 64);
    }
    if (wg == 0) { pacc[2 * cp] = acc0; pacc[2 * cp + 1] = acc1; }
    __syncthreads();
    if (t < 32) partial[(size_t)(b * 32 + t) * 1024 + d * 16 + hq] = pacc[t];
}

// ---- Fused attention + ifft: partial -> (attn per-block, redundant) -> keff bf16
// grid 432 * 256 covers 110592 K_eff elements; layout [b][tap][o][ic].
__global__ __launch_bounds__(256) void attn_ifft_kernel(const float* __restrict__ partial,
                                                        const float* __restrict__ freq,
                                                        const float* __restrict__ w1,
                                                        const float* __restrict__ b1,
                                                        const float* __restrict__ w2,
                                                        const float* __restrict__ b2,
                                                        short* __restrict__ keff) {
    __shared__ float red[256];
    __shared__ float pooled[64];
    __shared__ float hh[16], at[8], we[54];
    int t = threadIdx.x;
    {   // each of 4 threads per (b,c) pair sums 256 contiguous floats
        int p = t >> 2, q = t & 3;
        const float4* src = (const float4*)(partial + (size_t)p * 1024 + q * 256);
        float s = 0.f;
#pragma unroll
        for (int k = 0; k < 64; ++k) {
            float4 v = src[k];
            s += (v.x + v.y) + (v.z + v.w);
        }
        red[t] = s;
    }
    __syncthreads();
    if (t < 64) pooled[t] = (red[4*t] + red[4*t+1] + red[4*t+2] + red[4*t+3]) * (1.0f / (float)SPA);
    __syncthreads();
    if (t < 16) {
        int b = t >> 3, j = t & 7;
        float a = b1[j];
        for (int c = 0; c < 32; ++c) a += pooled[b * 32 + c] * w1[j * 32 + c];
        hh[t] = a > 0.f ? a : 0.f;
    }
    __syncthreads();
    if (t < 8) {
        int b = t >> 2, k = t & 3;
        float a = b2[k];
        for (int j = 0; j < 8; ++j) a += hh[b * 8 + j] * w2[k * 8 + j];
        at[t] = a;
    }
    __syncthreads();
    if (t < 2) {
        float l0 = at[t*4], l1 = at[t*4+1], l2 = at[t*4+2], l3 = at[t*4+3];
        float m = fmaxf(fmaxf(l0, l1), fmaxf(l2, l3));
        float e0 = expf(l0 - m), e1 = expf(l1 - m), e2 = expf(l2 - m), e3 = expf(l3 - m);
        float inv = 1.0f / (e0 + e1 + e2 + e3);
        at[t*4] = e0 * inv; at[t*4+1] = e1 * inv; at[t*4+2] = e2 * inv; at[t*4+3] = e3 * inv;
    }
    __syncthreads();
    if (t < 54) {
        int b = t / 27, m = t % 27;
        int z = m / 9, y = (m / 3) % 3, xx = m % 3;
        int n = (z > 0) + (y > 0) + (xx > 0);
        float w = 0.f;
        w += at[b*4 + 0] * ((n <= 1) ? 1.f : 0.f);
        w += at[b*4 + 1] * ((n == 2) ? 1.f : 0.f);
        w += at[b*4 + 2] * ((n >= 2) ? 1.f : 0.f);
        w += at[b*4 + 3] * ((n == 3) ? 1.f : 0.f);
        we[t] = w;
    }
    __syncthreads();
    // ifft main
    int idx = blockIdx.x * 256 + t;
    int i = idx & 31;
    int o = (idx >> 5) & 63;
    int bt = idx >> 11;
    int tp = bt % 27, b = bt / 27;
    int dk = tp / 9, hk = (tp / 3) % 3, wk = tp % 3;
    const float* f = freq + (size_t)(o * 32 + i) * 54;
    float s = 0.f;
#pragma unroll
    for (int z = 0; z < 3; ++z)
#pragma unroll
        for (int y = 0; y < 3; ++y)
#pragma unroll
            for (int xk = 0; xk < 3; ++xk) {
                int m = (dk * z + hk * y + wk * xk) % 3;
                float cm = (m == 0) ? 1.0f : -0.5f;
                float sm = (m == 0) ? 0.0f : ((m == 1) ? 0.8660254037844386f
                                                       : -0.8660254037844386f);
                int tap = z * 9 + y * 3 + xk;
                s += we[b * 27 + tap] * (f[tap * 2] * cm - f[tap * 2 + 1] * sm);
            }
    keff[idx] = f2bf(s * (1.0f / 27.0f));
}

// ---- Conv via bf16 MFMA, staging from pre-transposed xT ----
__global__ __launch_bounds__(256, 2) void conv_fast(const short* __restrict__ xT,
                                                    const short* __restrict__ keff,
                                                    const float* __restrict__ bias,
                                                    float* __restrict__ out) {
    __shared__ char xs[34560];   // [d6][h10][w18][ic16] bf16, XOR-swizzled

    int bid = blockIdx.x;        // 1024 = 4(w) * 8(h) * 16(d) * 2(b)
    int wblk = bid & 3;
    int hblk = (bid >> 2) & 7;
    int dblk = (bid >> 5) & 15;
    int b    = bid >> 9;
    int d0 = dblk * 4, h0 = hblk * 8, w0 = wblk * 16;

    int tid = threadIdx.x;
    int l = tid & 63, td = tid >> 6;

    f32x16 acc[2][4];
#pragma unroll
    for (int i = 0; i < 2; ++i)
#pragma unroll
        for (int j = 0; j < 4; ++j) acc[i][j] = f32x16{};

    int laneB = td * 5760 + ((l >> 4) & 1) * 576 + (l & 15) * 32 + (l >> 5) * 16;
    const short* Abase = keff + (size_t)b * 55296 + (l & 31) * 32 + (l >> 5) * 8;
    const short* xTb = xT + (size_t)b * 8388608;

    for (int chunk = 0; chunk < 2; ++chunk) {
        __syncthreads();
        // ---- stage: 2160 points x 32B, two 16B halves per point ----
        const short* xc = xTb + chunk * 16;
#pragma unroll
        for (int it = 0; it < 17; ++it) {
            int e = it * 256 + tid;
            if (e < 4320) {
                int p = e >> 1, hf = e & 1;
                int dd = p / 180, r = p - dd * 180;
                int hh2 = r / 18, ww2 = r - hh2 * 18;
                int gd = d0 - 1 + dd, gh = h0 - 1 + hh2, gw = w0 - 1 + ww2;
                s16x8 v = {};
                if ((unsigned)gd < 64u && (unsigned)gh < 64u && (unsigned)gw < 64u)
                    v = *(const s16x8*)(xc + ((gd * 64 + gh) * 64 + gw) * 32 + hf * 8);
                *(s16x8*)(xs + swz(e * 16)) = v;
            }
        }
        __syncthreads();

        // ---- compute: 27 taps, A prefetch distance 1 ----
        const short* A = Abase + chunk * 16;
        s16x8 a0 = *(const s16x8*)(A);
        s16x8 a1 = *(const s16x8*)(A + 1024);
#pragma unroll 1
        for (int tap = 0; tap < 27; ++tap) {
            int nxt = (tap < 26) ? tap + 1 : 26;
            s16x8 n0 = *(const s16x8*)(A + nxt * 2048);
            s16x8 n1 = *(const s16x8*)(A + nxt * 2048 + 1024);
            int kd = tap / 9, rr = tap - kd * 9;
            int kh = rr / 3, kw2 = rr - kh * 3;
            int off = laneB + kd * 5760 + kh * 576 + kw2 * 32;
            s16x8 B0 = *(const s16x8*)(xs + swz(off));
            s16x8 B1 = *(const s16x8*)(xs + swz(off + 1152));
            s16x8 B2 = *(const s16x8*)(xs + swz(off + 2304));
            s16x8 B3 = *(const s16x8*)(xs + swz(off + 3456));
            acc[0][0] = __builtin_amdgcn_mfma_f32_32x32x16_bf16(a0, B0, acc[0][0], 0, 0, 0);
            acc[1][0] = __builtin_amdgcn_mfma_f32_32x32x16_bf16(a1, B0, acc[1][0], 0, 0, 0);
            acc[0][1] = __builtin_amdgcn_mfma_f32_32x32x16_bf16(a0, B1, acc[0][1], 0, 0, 0);
            acc[1][1] = __builtin_amdgcn_mfma_f32_32x32x16_bf16(a1, B1, acc[1][1], 0, 0, 0);
            acc[0][2] = __builtin_amdgcn_mfma_f32_32x32x16_bf16(a0, B2, acc[0][2], 0, 0, 0);
            acc[1][2] = __builtin_amdgcn_mfma_f32_32x32x16_bf16(a1, B2, acc[1][2], 0, 0, 0);
            acc[0][3] = __builtin_amdgcn_mfma_f32_32x32x16_bf16(a0, B3, acc[0][3], 0, 0, 0);
            acc[1][3] = __builtin_amdgcn_mfma_f32_32x32x16_bf16(a1, B3, acc[1][3], 0, 0, 0);
            a0 = n0; a1 = n1;
        }
    }

    float bv[32];
#pragma unroll
    for (int ot = 0; ot < 2; ++ot)
#pragma unroll
        for (int reg = 0; reg < 16; ++reg)
            bv[ot * 16 + reg] = bias[ot * 32 + (reg & 3) + 8 * (reg >> 2) + 4 * (l >> 5)];

    int dd = d0 + td;
    int ww2 = w0 + (l & 15);
    int hbase = h0 + ((l >> 4) & 1);
#pragma unroll
    for (int ot = 0; ot < 2; ++ot)
#pragma unroll
        for (int s = 0; s < 4; ++s) {
#pragma unroll
            for (int reg = 0; reg < 16; ++reg) {
                int o = ot * 32 + (reg & 3) + 8 * (reg >> 2) + 4 * (l >> 5);
                size_t oidx = (((size_t)(b * OCH + o) * DIM + dd) * DIM
                               + (hbase + 2 * s)) * DIM + ww2;
                out[oidx] = acc[ot][s][reg] + bv[ot * 16 + reg];
            }
        }
}

// =================================================================
// LEGACY FALLBACK (round-2 path, used when ws_size is insufficient)
// =================================================================

__global__ __launch_bounds__(256) void pool_kernel(const float* __restrict__ x,
                                                   float* __restrict__ partial) {
    int bid = blockIdx.x;
    int pair = bid >> 5;
    int chunk = bid & 31;
    const float4* base = (const float4*)(x + (size_t)pair * SPA + (size_t)chunk * 8192);
    int tid = threadIdx.x;
    float s = 0.f;
#pragma unroll
    for (int k = 0; k < 8; ++k) {
        float4 v = base[k * 256 + tid];
        s += (v.x + v.y) + (v.z + v.w);
    }
#pragma unroll
    for (int off = 32; off > 0; off >>= 1) s += __shfl_down(s, off, 64);
    __shared__ float red[4];
    int lane = tid & 63, wv = tid >> 6;
    if (lane == 0) red[wv] = s;
    __syncthreads();
    if (tid == 0) partial[bid] = (red[0] + red[1]) + (red[2] + red[3]);
}

__global__ __launch_bounds__(64) void attn_kernel(const float* __restrict__ partial,
                                                  const float* __restrict__ w1,
                                                  const float* __restrict__ b1,
                                                  const float* __restrict__ w2,
                                                  const float* __restrict__ b2,
                                                  float* __restrict__ weff) {
    __shared__ float pl[64], hh[16], at[8];
    int t = threadIdx.x;
    {
        float s = 0.f;
#pragma unroll
        for (int k = 0; k < 32; ++k) s += partial[t * 32 + k];
        pl[t] = s * (1.0f / (float)SPA);
    }
    __syncthreads();
    if (t < 16) {
        int b = t >> 3, j = t & 7;
        float a = b1[j];
        for (int c = 0; c < 32; ++c) a += pl[b * 32 + c] * w1[j * 32 + c];
        hh[t] = a > 0.f ? a : 0.f;
    }
    __syncthreads();
    if (t < 8) {
        int b = t >> 2, k = t & 3;
        float a = b2[k];
        for (int j = 0; j < 8; ++j) a += hh[b * 8 + j] * w2[k * 8 + j];
        at[t] = a;
    }
    __syncthreads();
    if (t < 2) {
        float l0 = at[t*4], l1 = at[t*4+1], l2 = at[t*4+2], l3 = at[t*4+3];
        float m = fmaxf(fmaxf(l0, l1), fmaxf(l2, l3));
        float e0 = expf(l0 - m), e1 = expf(l1 - m), e2 = expf(l2 - m), e3 = expf(l3 - m);
        float inv = 1.0f / (e0 + e1 + e2 + e3);
        at[t*4] = e0 * inv; at[t*4+1] = e1 * inv; at[t*4+2] = e2 * inv; at[t*4+3] = e3 * inv;
    }
    __syncthreads();
    if (t < 54) {
        int b = t / 27, m = t % 27;
        int z = m / 9, y = (m / 3) % 3, xx = m % 3;
        int n = (z > 0) + (y > 0) + (xx > 0);
        float w = 0.f;
        w += at[b*4 + 0] * ((n <= 1) ? 1.f : 0.f);
        w += at[b*4 + 1] * ((n == 2) ? 1.f : 0.f);
        w += at[b*4 + 2] * ((n >= 2) ? 1.f : 0.f);
        w += at[b*4 + 3] * ((n == 3) ? 1.f : 0.f);
        weff[t] = w;
    }
}

__global__ __launch_bounds__(256) void ifft_kernel(const float* __restrict__ freq,
                                                   const float* __restrict__ weff,
                                                   short* __restrict__ keff) {
    int idx = blockIdx.x * 256 + threadIdx.x;
    int i = idx & 31;
    int o = (idx >> 5) & 63;
    int bt = idx >> 11;
    int t = bt % 27, b = bt / 27;
    int d = t / 9, h = (t / 3) % 3, w = t % 3;
    const float* f = freq + (size_t)(o * 32 + i) * 54;
    float s = 0.f;
#pragma unroll
    for (int z = 0; z < 3; ++z)
#pragma unroll
        for (int y = 0; y < 3; ++y)
#pragma unroll
            for (int xk = 0; xk < 3; ++xk) {
                int m = (d * z + h * y + w * xk) % 3;
                float cm = (m == 0) ? 1.0f : -0.5f;
                float sm = (m == 0) ? 0.0f : ((m == 1) ? 0.8660254037844386f
                                                       : -0.8660254037844386f);
                int tap = z * 9 + y * 3 + xk;
                s += weff[b * 27 + tap] * (f[tap * 2] * cm - f[tap * 2 + 1] * sm);
            }
    keff[idx] = f2bf(s * (1.0f / 27.0f));
}

__global__ __launch_bounds__(256, 2) void conv_mfma(const float* __restrict__ x,
                                                    const short* __restrict__ keff,
                                                    const float* __restrict__ bias,
                                                    float* __restrict__ out) {
    __shared__ char xs[34560];
    int bid = blockIdx.x;
    int wblk = bid & 3;
    int hblk = (bid >> 2) & 7;
    int dblk = (bid >> 5) & 15;
    int b    = bid >> 9;
    int d0 = dblk * 4, h0 = hblk * 8, w0 = wblk * 16;
    int tid = threadIdx.x;
    int l = tid & 63, td = tid >> 6;
    f32x16 acc[2][4];
#pragma unroll
    for (int i = 0; i < 2; ++i)
#pragma unroll
        for (int j = 0; j < 4; ++j) acc[i][j] = f32x16{};
    int laneB = td * 5760 + ((l >> 4) & 1) * 576 + (l & 15) * 32 + (l >> 5) * 16;
    const short* Abase = keff + (size_t)b * 55296 + (l & 31) * 32 + (l >> 5) * 8;
    int p0 = tid >> 1, half = tid & 1;
    for (int chunk = 0; chunk < 2; ++chunk) {
        __syncthreads();
        const float* xc = x + (size_t)(b * ICH + chunk * 16 + half * 8) * SPA;
#pragma unroll
        for (int it = 0; it < 9; ++it) {
            int e = it * 256 + tid;
            if (e < 2160) {
                int p = it * 128 + p0;
                int dd = p / 180, r = p - dd * 180;
                int hh2 = r / 18, ww2 = r - hh2 * 18;
                int gd = d0 - 1 + dd, gh = h0 - 1 + hh2, gw = w0 - 1 + ww2;
                s16x8 v = {};
                if ((unsigned)gd < 64u && (unsigned)gh < 64u && (unsigned)gw < 64u) {
                    const float* xp = xc + (((gd * 64) + gh) * 64 + gw);
#pragma unroll
                    for (int j = 0; j < 8; ++j) v[j] = f2bf(xp[(size_t)j * SPA]);
                }
                *(s16x8*)(xs + swz(e * 16)) = v;
            }
        }
        __syncthreads();
        const short* A = Abase + chunk * 16;
        s16x8 a0 = *(const s16x8*)(A);
        s16x8 a1 = *(const s16x8*)(A + 1024);
#pragma unroll 1
        for (int tap = 0; tap < 27; ++tap) {
            int nxt = (tap < 26) ? tap + 1 : 26;
            s16x8 n0 = *(const s16x8*)(A + nxt * 2048);
            s16x8 n1 = *(const s16x8*)(A + nxt * 2048 + 1024);
            int kd = tap / 9, rr = tap - kd * 9;
            int kh = rr / 3, kw2 = rr - kh * 3;
            int off = laneB + kd * 5760 + kh * 576 + kw2 * 32;
            s16x8 B0 = *(const s16x8*)(xs + swz(off));
            s16x8 B1 = *(const s16x8*)(xs + swz(off + 1152));
            s16x8 B2 = *(const s16x8*)(xs + swz(off + 2304));
            s16x8 B3 = *(const s16x8*)(xs + swz(off + 3456));
            acc[0][0] = __builtin_amdgcn_mfma_f32_32x32x16_bf16(a0, B0, acc[0][0], 0, 0, 0);
            acc[1][0] = __builtin_amdgcn_mfma_f32_32x32x16_bf16(a1, B0, acc[1][0], 0, 0, 0);
            acc[0][1] = __builtin_amdgcn_mfma_f32_32x32x16_bf16(a0, B1, acc[0][1], 0, 0, 0);
            acc[1][1] = __builtin_amdgcn_mfma_f32_32x32x16_bf16(a1, B1, acc[1][1], 0, 0, 0);
            acc[0][2] = __builtin_amdgcn_mfma_f32_32x32x16_bf16(a0, B2, acc[0][2], 0, 0, 0);
            acc[1][2] = __builtin_amdgcn_mfma_f32_32x32x16_bf16(a1, B2, acc[1][2], 0, 0, 0);
            acc[0][3] = __builtin_amdgcn_mfma_f32_32x32x16_bf16(a0, B3, acc[0][3], 0, 0, 0);
            acc[1][3] = __builtin_amdgcn_mfma_f32_32x32x16_bf16(a1, B3, acc[1][3], 0, 0, 0);
            a0 = n0; a1 = n1;
        }
    }
    float bv[32];
#pragma unroll
    for (int ot = 0; ot < 2; ++ot)
#pragma unroll
        for (int reg = 0; reg < 16; ++reg)
            bv[ot * 16 + reg] = bias[ot * 32 + (reg & 3) + 8 * (reg >> 2) + 4 * (l >> 5)];
    int dd = d0 + td;
    int ww2 = w0 + (l & 15);
    int hbase = h0 + ((l >> 4) & 1);
#pragma unroll
    for (int ot = 0; ot < 2; ++ot)
#pragma unroll
        for (int s = 0; s < 4; ++s) {
#pragma unroll
            for (int reg = 0; reg < 16; ++reg) {
                int o = ot * 32 + (reg & 3) + 8 * (reg >> 2) + 4 * (l >> 5);
                size_t oidx = (((size_t)(b * OCH + o) * DIM + dd) * DIM
                               + (hbase + 2 * s)) * DIM + ww2;
                out[oidx] = acc[ot][s][reg] + bv[ot * 16 + reg];
            }
        }
}

extern "C" void kernel_launch(void* const* d_in, const int* in_sizes, int n_in,
                              void* d_out, int out_size, void* d_ws, size_t ws_size,
                              hipStream_t stream) {
    const float* x    = (const float*)d_in[0];
    const float* freq = (const float*)d_in[1];
    const float* w1   = (const float*)d_in[2];
    const float* b1   = (const float*)d_in[3];
    const float* w2   = (const float*)d_in[4];
    const float* b2   = (const float*)d_in[5];
    const float* bias = (const float*)d_in[6];
    float* out = (float*)d_out;
    char* ws = (char*)d_ws;

    const size_t NEED = 524288 + (size_t)2 * 64 * 64 * 64 * 32 * 2;  // 67.6 MB
    if (ws_size >= NEED) {
        float* partial = (float*)ws;                 // 65536 f32 = 256 KB
        short* keff    = (short*)(ws + 262144);      // 110592 bf16 = 216 KB
        short* xT      = (short*)(ws + 524288);      // 67.1 MB

        prepass_kernel<<<2048, 256, 0, stream>>>(x, xT, partial);
        attn_ifft_kernel<<<432, 256, 0, stream>>>(partial, freq, w1, b1, w2, b2, keff);
        conv_fast<<<1024, 256, 0, stream>>>(xT, keff, bias, out);
    } else {
        float* partial = (float*)ws;                 // 2048 f32
        float* weff    = (float*)(ws + 8192);        // 54 f32
        short* keff    = (short*)(ws + 8448);        // 110592 bf16

        pool_kernel<<<2048, 256, 0, stream>>>(x, partial);
        attn_kernel<<<1, 64, 0, stream>>>(partial, w1, b1, w2, b2, weff);
        ifft_kernel<<<432, 256, 0, stream>>>(freq, weff, keff);
        conv_mfma<<<1024, 256, 0, stream>>>(x, keff, bias, out);
    }
}